// Round 9
// baseline (385.948 us; speedup 1.0000x reference)
//
#include <hip/hip_runtime.h>
#include <hip/hip_fp16.h>

typedef unsigned long long ull;
typedef unsigned int uint;

#define BLOCK 256
#define CHUNK 8192    // edges per p1/p3 block
#define BN 128        // nodes per destination bucket
#define PB 128        // nodes per pooling block
#define WINV (1.0f / 32768.0f)

// ---- init: zero sums/cnt, set rowptr tail ----
__global__ void init_kernel(float* __restrict__ sums, float* __restrict__ cnt,
                            int* __restrict__ rowptr, int G, int nN, int nE) {
    int i = blockIdx.x * BLOCK + threadIdx.x;
    if (i < G * 32) sums[i] = 0.f;
    if (i < G) cnt[i] = 0.f;
    if (i == 0) rowptr[nN] = nE;
}

// ---- p1: per-chunk bucket histogram (LDS atomics only) ----
__global__ void p1_kernel(const int* __restrict__ col, int* __restrict__ cntmat,
                          int nE, int NBUK) {
    __shared__ int hist[1024];
    for (int i = threadIdx.x; i < NBUK; i += BLOCK) hist[i] = 0;
    __syncthreads();
    int base = blockIdx.x * CHUNK;
    int end = min(base + CHUNK, nE);
    for (int e = base + threadIdx.x; e < end; e += BLOCK)
        atomicAdd(&hist[col[e] >> 7], 1);
    __syncthreads();
    for (int i = threadIdx.x; i < NBUK; i += BLOCK)
        cntmat[(size_t)blockIdx.x * NBUK + i] = hist[i];
}

// ---- p2a: per-bucket scan over chunks, one wave per bucket (generic) ----
__global__ void p2a_kernel(int* __restrict__ cntmat, int* __restrict__ tot, int C, int NBUK) {
    int wv = threadIdx.x >> 6, lane = threadIdx.x & 63;
    int b = blockIdx.x * 4 + wv;
    if (b >= NBUK) return;
    int running = 0;
    for (int seg = 0; seg < C; seg += 64) {
        int c = seg + lane;
        int v = (c < C) ? cntmat[(size_t)c * NBUK + b] : 0;
        int s = v;
#pragma unroll
        for (int off = 1; off < 64; off <<= 1) {
            int u = __shfl_up(s, off);
            if (lane >= off) s += u;
        }
        if (c < C) cntmat[(size_t)c * NBUK + b] = running + (s - v);
        running += __shfl(s, 63);
    }
    if (lane == 0) tot[b] = running;
}

// ---- p2b: exclusive scan of totals -> base[] (generic) ----
__global__ void p2b_kernel(const int* __restrict__ tot, int* __restrict__ bb, int NBUK, int total) {
    __shared__ int s[1024];
    int t = threadIdx.x;
    int v = (t < NBUK) ? tot[t] : 0;
    s[t] = v;
    __syncthreads();
    for (int off = 1; off < 1024; off <<= 1) {
        int u = (t >= off) ? s[t - off] : 0;
        __syncthreads();
        s[t] += u;
        __syncthreads();
    }
    if (t < NBUK) bb[t] = s[t] - v;
    if (t == 0) bb[NBUK] = total;
}

// ---- p3: scatter edges into bucket-sorted order ----
// entry = [dl:7][src:17] << 32 | fp32(w)
__global__ void p3_kernel(const int* __restrict__ row, const int* __restrict__ col,
                          const float* __restrict__ w, const int* __restrict__ cntmat,
                          const int* __restrict__ bb, ull* __restrict__ sorted,
                          int nE, int NBUK) {
    __shared__ int cur[1024];
    for (int i = threadIdx.x; i < NBUK; i += BLOCK)
        cur[i] = cntmat[(size_t)blockIdx.x * NBUK + i] + bb[i];
    __syncthreads();
    int base = blockIdx.x * CHUNK;
    int end = min(base + CHUNK, nE);
    for (int e = base + threadIdx.x; e < end; e += BLOCK) {
        int c = col[e], r = row[e];
        float ww = w[e];
        int b = c >> 7;
        int rk = atomicAdd(&cur[b], 1);
        ull ent = ((ull)(((uint)(c & 127) << 17) | (uint)r) << 32) | (ull)__float_as_uint(ww);
        sorted[rk] = ent;
    }
}

// ---- p4 (merged): degree+dinv+rowptr, then 4-byte csr [src:17][w:15] ----
__global__ void p4_kernel(const ull* __restrict__ sorted, const int* __restrict__ bb,
                          float* __restrict__ dinv, int* __restrict__ rowptr,
                          uint* __restrict__ csr4, int nN) {
    __shared__ float wsum[BN];
    __shared__ int cntL[BN];
    __shared__ int scanS[BN];
    __shared__ int cur[BN];
    if (threadIdx.x < BN) { wsum[threadIdx.x] = 0.f; cntL[threadIdx.x] = 0; }
    __syncthreads();
    int b = blockIdx.x;
    int e0 = bb[b], e1 = bb[b + 1];
    for (int i = e0 + threadIdx.x; i < e1; i += BLOCK) {
        ull ent = sorted[i];
        int dl = (int)(ent >> 49) & 127;
        atomicAdd(&cntL[dl], 1);
        atomicAdd(&wsum[dl], __uint_as_float((uint)ent));
    }
    __syncthreads();
    if (threadIdx.x < BN) scanS[threadIdx.x] = cntL[threadIdx.x];
    __syncthreads();
    for (int off = 1; off < BN; off <<= 1) {
        int u = 0;
        if (threadIdx.x < BN && threadIdx.x >= off) u = scanS[threadIdx.x - off];
        __syncthreads();
        if (threadIdx.x < BN) scanS[threadIdx.x] += u;
        __syncthreads();
    }
    if (threadIdx.x < BN) {
        int n = b * BN + threadIdx.x;
        if (n < nN) {
            dinv[n] = rsqrtf(1.0f + wsum[threadIdx.x]);
            int rp = e0 + scanS[threadIdx.x] - cntL[threadIdx.x];
            rowptr[n] = rp;
            cur[threadIdx.x] = rp;
        }
    }
    __syncthreads();
    for (int i = e0 + threadIdx.x; i < e1; i += BLOCK) {
        ull ent = sorted[i];           // L2-hot re-read
        int dl = (int)(ent >> 49) & 127;
        uint src = (uint)(ent >> 32) & 0x1FFFFu;
        float ww = __uint_as_float((uint)ent);
        int wq = min((int)(ww * 32768.0f + 0.5f), 32767);
        int pos = atomicAdd(&cur[dl], 1);
        csr4[pos] = (src << 15) | (uint)wq;
    }
}

// ---- q1/q3: degree-grouped node permutation (64 degree bins) ----
__global__ void q1_kernel(const int* __restrict__ rowptr, int* __restrict__ cntmatN, int nN) {
    __shared__ int hist[64];
    if (threadIdx.x < 64) hist[threadIdx.x] = 0;
    __syncthreads();
    int n = blockIdx.x * BLOCK + threadIdx.x;
    if (n < nN) atomicAdd(&hist[min(rowptr[n + 1] - rowptr[n], 63)], 1);
    __syncthreads();
    if (threadIdx.x < 64) cntmatN[blockIdx.x * 64 + threadIdx.x] = hist[threadIdx.x];
}

__global__ void q3_kernel(const int* __restrict__ rowptr, const int* __restrict__ cntmatN,
                          const int* __restrict__ bbN, int* __restrict__ order, int nN) {
    __shared__ int cur[64];
    if (threadIdx.x < 64)
        cur[threadIdx.x] = cntmatN[blockIdx.x * 64 + threadIdx.x] + bbN[threadIdx.x];
    __syncthreads();
    int n = blockIdx.x * BLOCK + threadIdx.x;
    if (n < nN) {
        int rk = atomicAdd(&cur[min(rowptr[n + 1] - rowptr[n], 63)], 1);
        order[rk] = n;
    }
}

// ---- ux: u_x = dinv * x (fp32, 4-wide, 1.6 MB L2-resident) ----
__global__ void ux_kernel(const float* __restrict__ x, const float* __restrict__ dinv,
                          float* __restrict__ u_x, int nN) {
    int i = blockIdx.x * BLOCK + threadIdx.x;
    if (i < nN * 4) u_x[i] = x[i] * dinv[i >> 2];
}

// ---- layer 1: agg(u_x)*di @ W1 + b1, relu, @W2, *di -> u2 fp16 ----
__global__ void layer1_pass(const float* __restrict__ u_x, const int* __restrict__ rowptr,
                            const uint* __restrict__ csr4, const float* __restrict__ dinv,
                            const int* __restrict__ order,
                            const float* __restrict__ W1, const float* __restrict__ b1,
                            const float* __restrict__ W2, __half* __restrict__ t_next, int nN) {
    __shared__ float W1s[4 * 32];
    __shared__ float W2s[32 * 32];
    __shared__ float b1s[32];
    __shared__ float hS[BLOCK / 64][32];
    if (threadIdx.x < 128) W1s[threadIdx.x] = W1[threadIdx.x];
    for (int i = threadIdx.x; i < 32 * 32; i += BLOCK) W2s[i] = W2[i];
    if (threadIdx.x < 32) b1s[threadIdx.x] = b1[threadIdx.x];
    __syncthreads();

    int wv = threadIdx.x >> 6, lane = threadIdx.x & 63;
    int widx = blockIdx.x * (BLOCK / 64) + wv;
    if (widx >= nN) return;
    int n = order[widx];                        // degree-grouped schedule

    int el = lane >> 2, comp = lane & 3;        // 16 edge slots x 4 components
    float di = dinv[n];
    int s0 = rowptr[n], s1 = rowptr[n + 1];
    float acc = (el == 0) ? u_x[(size_t)n * 4 + comp] : 0.0f;   // self: u_x[n]
    int j = s0;
    for (; j + 32 <= s1; j += 32) {
        uint ea = csr4[j + el], eb = csr4[j + 16 + el];
        acc = fmaf((float)(ea & 32767u) * WINV, u_x[(size_t)(ea >> 15) * 4 + comp], acc);
        acc = fmaf((float)(eb & 32767u) * WINV, u_x[(size_t)(eb >> 15) * 4 + comp], acc);
    }
    for (; j + 16 <= s1; j += 16) {
        uint e = csr4[j + el];
        acc = fmaf((float)(e & 32767u) * WINV, u_x[(size_t)(e >> 15) * 4 + comp], acc);
    }
    if (j + el < s1) {
        uint e = csr4[j + el];
        acc = fmaf((float)(e & 32767u) * WINV, u_x[(size_t)(e >> 15) * 4 + comp], acc);
    }
#pragma unroll
    for (int off = 4; off < 64; off <<= 1) acc += __shfl_xor(acc, off);
    float a0 = di * __shfl(acc, 0), a1 = di * __shfl(acc, 1);
    float a2c = di * __shfl(acc, 2), a3 = di * __shfl(acc, 3);

    int f = lane & 31, e2 = lane >> 5;
    float h = b1s[f];
    h = fmaf(a0, W1s[0 * 32 + f], h);
    h = fmaf(a1, W1s[1 * 32 + f], h);
    h = fmaf(a2c, W1s[2 * 32 + f], h);
    h = fmaf(a3, W1s[3 * 32 + f], h);
    h = fmaxf(h, 0.0f);
    if (lane < 32) hS[wv][f] = h;               // wave-private; DS ops in-order
    float o = 0.0f;
#pragma unroll
    for (int k = 0; k < 16; ++k) {
        int kk = e2 * 16 + k;
        o = fmaf(hS[wv][kk], W2s[kk * 32 + f], o);
    }
    o += __shfl_xor(o, 32);
    if (lane < 32) t_next[(size_t)n * 32 + f] = __float2half(di * o);   // u-table
}

// ---- fused layer pass over fp16 u-table: h = di*(Σ w·u[src] + u[n]) + b ----
template <bool LAST>
__global__ void layer_pass(const __half* __restrict__ t, const int* __restrict__ rowptr,
                           const uint* __restrict__ csr4, const float* __restrict__ dinv,
                           const int* __restrict__ order,
                           const float* __restrict__ b, const float* __restrict__ W,
                           __half* __restrict__ t_next, __half* __restrict__ stage, int nN) {
    __shared__ float Ws[32 * 32];
    __shared__ float hS[BLOCK / 64][32];
    if (!LAST) {
        for (int i = threadIdx.x; i < 32 * 32; i += BLOCK) Ws[i] = W[i];
        __syncthreads();
    }
    int wv = threadIdx.x >> 6, lane = threadIdx.x & 63;
    int e2 = lane >> 5, f = lane & 31;
    int widx = blockIdx.x * (BLOCK / 64) + wv;
    if (widx >= nN) return;
    int n = order[widx];                        // degree-grouped schedule

    float di = dinv[n];
    int s0 = rowptr[n], s1 = rowptr[n + 1];
    float acc = (e2 == 0) ? __half2float(t[(size_t)n * 32 + f]) : 0.0f;   // self: u[n]

    int j4 = s0;
    for (; j4 + 16 <= s1; j4 += 16) {           // 16 edges in flight per wave
        uint p[8]; float v[8];
#pragma unroll
        for (int u = 0; u < 8; ++u) p[u] = csr4[j4 + 2 * u + e2];
#pragma unroll
        for (int u = 0; u < 8; ++u) v[u] = __half2float(t[(size_t)(p[u] >> 15) * 32 + f]);
#pragma unroll
        for (int u = 0; u < 8; ++u) acc = fmaf((float)(p[u] & 32767u) * WINV, v[u], acc);
    }
    for (; j4 + 4 <= s1; j4 += 4) {
        uint p[2]; float v[2];
#pragma unroll
        for (int u = 0; u < 2; ++u) p[u] = csr4[j4 + 2 * u + e2];
#pragma unroll
        for (int u = 0; u < 2; ++u) v[u] = __half2float(t[(size_t)(p[u] >> 15) * 32 + f]);
#pragma unroll
        for (int u = 0; u < 2; ++u) acc = fmaf((float)(p[u] & 32767u) * WINV, v[u], acc);
    }
    for (int j = j4 + e2; j < s1; j += 2) {
        uint p = csr4[j];
        acc = fmaf((float)(p & 32767u) * WINV, __half2float(t[(size_t)(p >> 15) * 32 + f]), acc);
    }

    acc += __shfl_xor(acc, 32);
    float h = di * acc + b[f];

    if (LAST) {
        if (lane < 32) stage[(size_t)n * 32 + f] = __float2half(h);
    } else {
        h = fmaxf(h, 0.0f);
        if (lane < 32) hS[wv][f] = h;
        float o = 0.0f;
#pragma unroll
        for (int k = 0; k < 16; ++k) {
            int kk = e2 * 16 + k;
            o = fmaf(hS[wv][kk], Ws[kk * 32 + f], o);
        }
        o += __shfl_xor(o, 32);
        if (lane < 32) t_next[(size_t)n * 32 + f] = __float2half(di * o);   // u-table
    }
}

// ---- pooling: LDS-privatized windows (batch sorted), fp16 input ----
__global__ void pool_kernel(const __half* __restrict__ stage, const int* __restrict__ batch,
                            float* __restrict__ sums, float* __restrict__ cnt, int nN) {
    __shared__ float accS[PB][32];
    __shared__ float cntS[PB];
    __shared__ int g0s;
    int n0 = blockIdx.x * PB;
    for (int i = threadIdx.x; i < PB * 32; i += BLOCK) ((float*)accS)[i] = 0.0f;
    for (int i = threadIdx.x; i < PB; i += BLOCK) cntS[i] = 0.0f;
    if (threadIdx.x == 0) g0s = batch[n0];
    __syncthreads();
    int g0 = g0s;
    int f = threadIdx.x & 31, sub = threadIdx.x >> 5;
    for (int k = 0; k < PB / 8; ++k) {
        int n = n0 + sub + k * 8;
        if (n < nN) {
            int g = batch[n];
            int off = g - g0;
            float v = __half2float(stage[(size_t)n * 32 + f]);
            if (off < PB) {
                atomicAdd(&accS[off][f], v);
                if (f == 0) atomicAdd(&cntS[off], 1.0f);
            } else {
                atomicAdd(&sums[(size_t)g * 32 + f], v);
                if (f == 0) atomicAdd(&cnt[g], 1.0f);
            }
        }
    }
    __syncthreads();
    int nLast = min(n0 + PB, nN) - 1;
    int range = min(batch[nLast] - g0, PB - 1);
    for (int s = sub; s <= range; s += 8) {
        atomicAdd(&sums[(size_t)(g0 + s) * 32 + f], accS[s][f]);
        if (f == 0) atomicAdd(&cnt[g0 + s], cntS[s]);
    }
}

// ---- classifier ----
__global__ void final_kernel(const float* __restrict__ sums, const float* __restrict__ cnt,
                             const float* __restrict__ lin_w, const float* __restrict__ lin_b,
                             float* __restrict__ out, int G) {
    int g = blockIdx.x * blockDim.x + threadIdx.x;
    if (g >= G) return;
    float c = fmaxf(cnt[g], 1.0f);
    float inv = 1.0f / c;
    float l0 = lin_b[0], l1 = lin_b[1], l2 = lin_b[2];
#pragma unroll
    for (int f = 0; f < 32; ++f) {
        float m = sums[g * 32 + f] * inv;
        l0 = fmaf(m, lin_w[f * 3 + 0], l0);
        l1 = fmaf(m, lin_w[f * 3 + 1], l1);
        l2 = fmaf(m, lin_w[f * 3 + 2], l2);
    }
    float mx = fmaxf(l0, fmaxf(l1, l2));
    float e0 = expf(l0 - mx), e1 = expf(l1 - mx), e2 = expf(l2 - mx);
    float s = 1.0f / (e0 + e1 + e2);
    out[g * 3 + 0] = e0 * s;
    out[g * 3 + 1] = e1 * s;
    out[g * 3 + 2] = e2 * s;
}

// ---------------- launch ----------------

extern "C" void kernel_launch(void* const* d_in, const int* in_sizes, int n_in,
                              void* d_out, int out_size, void* d_ws, size_t ws_size,
                              hipStream_t stream) {
    const float* x     = (const float*)d_in[0];
    const int*   ei    = (const int*)d_in[1];
    const float* ew    = (const float*)d_in[2];
    const int*   batch = (const int*)d_in[3];
    const float* W1    = (const float*)d_in[4];
    const float* b1    = (const float*)d_in[5];
    const float* W2    = (const float*)d_in[6];
    const float* b2    = (const float*)d_in[7];
    const float* W3    = (const float*)d_in[8];
    const float* b3    = (const float*)d_in[9];
    const float* lin_w = (const float*)d_in[10];
    const float* lin_b = (const float*)d_in[11];
    float* out = (float*)d_out;

    const int nN = in_sizes[0] / 4;       // 100000
    const int nE = in_sizes[2];           // 2500000
    const int G  = out_size / 3;          // 1000
    const int* row = ei;
    const int* col = ei + nE;

    const int NBUK = (nN + BN - 1) / BN;          // 782
    const int C    = (nE + CHUNK - 1) / CHUNK;    // 306
    const int NCN  = (nN + BLOCK - 1) / BLOCK;    // 391 node chunks

    // workspace layout (8B-aligned first)
    char* wsb = (char*)d_ws;
    ull*    sorted = (ull*)wsb;                                  // [nE]    20 MB
    uint*   csr4   = (uint*)(sorted + nE);                       // [nE]    10 MB
    float*  u_x    = (float*)(csr4 + nE);                        // [nN*4]  1.6 MB
    __half* t_a    = (__half*)(u_x + (size_t)nN * 4);            // [nN*32] 6.4 MB
    __half* t_b    = t_a + (size_t)nN * 32;                      // [nN*32] 6.4 MB
    __half* stage  = t_b + (size_t)nN * 32;                      // [nN*32] 6.4 MB
    int*    cntmat = (int*)(stage + (size_t)nN * 32);            // [C*NBUK] ~1 MB
    int*    tot    = cntmat + (size_t)C * NBUK;                  // [NBUK]
    int*    bb     = tot + NBUK;                                 // [NBUK+1]
    float*  dinv   = (float*)(bb + NBUK + 1);                    // [nN]
    int*    rowptr = (int*)(dinv + nN);                          // [nN+1]
    int*    order  = rowptr + nN + 1;                            // [nN]
    int*    cntmatN= order + nN;                                 // [NCN*64]
    int*    totN   = cntmatN + (size_t)NCN * 64;                 // [64]
    int*    bbN    = totN + 64;                                  // [65]
    float*  sums   = (float*)(bbN + 65);                         // [G*32]
    float*  cnt    = sums + (size_t)G * 32;                      // [G]

    const int gW = (nN + (BLOCK / 64) - 1) / (BLOCK / 64);       // one wave per node

    // ---- build ----
    init_kernel<<<(G * 32 + BLOCK - 1) / BLOCK, BLOCK, 0, stream>>>(sums, cnt, rowptr, G, nN, nE);
    p1_kernel<<<C, BLOCK, 0, stream>>>(col, cntmat, nE, NBUK);
    p2a_kernel<<<(NBUK + 3) / 4, BLOCK, 0, stream>>>(cntmat, tot, C, NBUK);
    p2b_kernel<<<1, 1024, 0, stream>>>(tot, bb, NBUK, nE);
    p3_kernel<<<C, BLOCK, 0, stream>>>(row, col, ew, cntmat, bb, sorted, nE, NBUK);
    p4_kernel<<<NBUK, BLOCK, 0, stream>>>(sorted, bb, dinv, rowptr, csr4, nN);
    ux_kernel<<<(nN * 4 + BLOCK - 1) / BLOCK, BLOCK, 0, stream>>>(x, dinv, u_x, nN);

    // ---- degree-grouped node order ----
    q1_kernel<<<NCN, BLOCK, 0, stream>>>(rowptr, cntmatN, nN);
    p2a_kernel<<<16, BLOCK, 0, stream>>>(cntmatN, totN, NCN, 64);
    p2b_kernel<<<1, 1024, 0, stream>>>(totN, bbN, 64, nN);
    q3_kernel<<<NCN, BLOCK, 0, stream>>>(rowptr, cntmatN, bbN, order, nN);

    // ---- layers ----
    layer1_pass<<<gW, BLOCK, 0, stream>>>(u_x, rowptr, csr4, dinv, order, W1, b1, W2, t_b, nN);
    layer_pass<false><<<gW, BLOCK, 0, stream>>>(t_b, rowptr, csr4, dinv, order, b2, W3, t_a, nullptr, nN);
    layer_pass<true><<<gW, BLOCK, 0, stream>>>(t_a, rowptr, csr4, dinv, order, b3, nullptr, nullptr, stage, nN);

    // ---- pooling + classifier ----
    pool_kernel<<<(nN + PB - 1) / PB, BLOCK, 0, stream>>>(stage, batch, sums, cnt, nN);
    final_kernel<<<(G + BLOCK - 1) / BLOCK, BLOCK, 0, stream>>>(sums, cnt, lin_w, lin_b, out, G);
}

// Round 10
// 377.293 us; speedup vs baseline: 1.0229x; 1.0229x over previous
//
#include <hip/hip_runtime.h>
#include <hip/hip_fp16.h>

typedef unsigned long long ull;
typedef unsigned int uint;

#define BLOCK 256
#define CHUNK 8192    // edges per p1 chunk
#define BN 128        // nodes per destination bucket
#define PB 128        // nodes per pooling block
#define WINV (1.0f / 32768.0f)

// ---- init: zero sums/cnt, set rowptr tail ----
__global__ void init_kernel(float* __restrict__ sums, float* __restrict__ cnt,
                            int* __restrict__ rowptr, int G, int nN, int nE) {
    int i = blockIdx.x * BLOCK + threadIdx.x;
    if (i < G * 32) sums[i] = 0.f;
    if (i < G) cnt[i] = 0.f;
    if (i == 0) rowptr[nN] = nE;
}

// ---- p1: per-chunk bucket histogram (LDS atomics only) ----
__global__ void p1_kernel(const int* __restrict__ col, int* __restrict__ cntmat,
                          int nE, int NBUK) {
    __shared__ int hist[1024];
    for (int i = threadIdx.x; i < NBUK; i += BLOCK) hist[i] = 0;
    __syncthreads();
    int base = blockIdx.x * CHUNK;
    int end = min(base + CHUNK, nE);
    for (int e = base + threadIdx.x; e < end; e += BLOCK)
        atomicAdd(&hist[col[e] >> 7], 1);
    __syncthreads();
    for (int i = threadIdx.x; i < NBUK; i += BLOCK)
        cntmat[(size_t)blockIdx.x * NBUK + i] = hist[i];
}

// ---- p2a: per-bucket scan over chunks, one wave per bucket ----
__global__ void p2a_kernel(int* __restrict__ cntmat, int* __restrict__ tot, int C, int NBUK) {
    int wv = threadIdx.x >> 6, lane = threadIdx.x & 63;
    int b = blockIdx.x * 4 + wv;
    if (b >= NBUK) return;
    int running = 0;
    for (int seg = 0; seg < C; seg += 64) {
        int c = seg + lane;
        int v = (c < C) ? cntmat[(size_t)c * NBUK + b] : 0;
        int s = v;
#pragma unroll
        for (int off = 1; off < 64; off <<= 1) {
            int u = __shfl_up(s, off);
            if (lane >= off) s += u;
        }
        if (c < C) cntmat[(size_t)c * NBUK + b] = running + (s - v);
        running += __shfl(s, 63);
    }
    if (lane == 0) tot[b] = running;
}

// ---- p2b: exclusive scan of totals -> base[] ----
__global__ void p2b_kernel(const int* __restrict__ tot, int* __restrict__ bb, int NBUK, int total) {
    __shared__ int s[1024];
    int t = threadIdx.x;
    int v = (t < NBUK) ? tot[t] : 0;
    s[t] = v;
    __syncthreads();
    for (int off = 1; off < 1024; off <<= 1) {
        int u = (t >= off) ? s[t - off] : 0;
        __syncthreads();
        s[t] += u;
        __syncthreads();
    }
    if (t < NBUK) bb[t] = s[t] - v;
    if (t == 0) bb[NBUK] = total;
}

// ---- p3: scatter edges into bucket-sorted order, quantizing w at the source ----
// csrE[pos] = src<<15 | wq(15b) ; dl8[pos] = dest&127.
// Each block handles 2 consecutive chunks (cur carries over exactly).
__global__ void p3_kernel(const int* __restrict__ row, const int* __restrict__ col,
                          const float* __restrict__ w, const int* __restrict__ cntmat,
                          const int* __restrict__ bb, uint* __restrict__ csrE,
                          unsigned char* __restrict__ dl8, int nE, int NBUK) {
    __shared__ int cur[1024];
    int c0 = blockIdx.x * 2;
    for (int i = threadIdx.x; i < NBUK; i += BLOCK)
        cur[i] = cntmat[(size_t)c0 * NBUK + i] + bb[i];
    __syncthreads();
    int base = c0 * CHUNK;
    int end = min(base + 2 * CHUNK, nE);
    for (int e = base + threadIdx.x; e < end; e += BLOCK) {
        int c = col[e], r = row[e];
        float ww = w[e];
        int b = c >> 7;
        int wq = min((int)(ww * 32768.0f + 0.5f), 32767);
        int pos = atomicAdd(&cur[b], 1);
        csrE[pos] = ((uint)r << 15) | (uint)wq;
        dl8[pos] = (unsigned char)(c & 127);
    }
}

// ---- p4: degree(from wq)+dinv+rowptr (1 packed LDS atomic/edge), then final
//      per-node csr4 (bucket-local permutation of csrE), plus u_x epilogue ----
__global__ void p4_kernel(const uint* __restrict__ csrE, const unsigned char* __restrict__ dl8,
                          const int* __restrict__ bb, const float* __restrict__ x,
                          float* __restrict__ u_x, float* __restrict__ dinv,
                          int* __restrict__ rowptr, uint* __restrict__ csr4, int nN) {
    __shared__ uint pk[BN];        // cnt<<24 | sum(wq)  (sum < 2^24 for deg<512)
    __shared__ int scanS[BN];
    __shared__ int cur[BN];
    if (threadIdx.x < BN) pk[threadIdx.x] = 0u;
    __syncthreads();
    int b = blockIdx.x;
    int e0 = bb[b], e1 = bb[b + 1];
    for (int i = e0 + threadIdx.x; i < e1; i += BLOCK)
        atomicAdd(&pk[dl8[i]], (1u << 24) | (csrE[i] & 32767u));
    __syncthreads();
    int cnt = 0;
    if (threadIdx.x < BN) { cnt = (int)(pk[threadIdx.x] >> 24); scanS[threadIdx.x] = cnt; }
    __syncthreads();
    for (int off = 1; off < BN; off <<= 1) {
        int u = 0;
        if (threadIdx.x < BN && threadIdx.x >= off) u = scanS[threadIdx.x - off];
        __syncthreads();
        if (threadIdx.x < BN) scanS[threadIdx.x] += u;
        __syncthreads();
    }
    if (threadIdx.x < BN) {
        int n = b * BN + threadIdx.x;
        if (n < nN) {
            float di = rsqrtf(1.0f + (float)(pk[threadIdx.x] & 0xFFFFFFu) * WINV);
            dinv[n] = di;
            int rp = e0 + scanS[threadIdx.x] - cnt;
            rowptr[n] = rp;
            cur[threadIdx.x] = rp;
            float4 xv = ((const float4*)x)[n];
            ((float4*)u_x)[n] = make_float4(xv.x * di, xv.y * di, xv.z * di, xv.w * di);
        }
    }
    __syncthreads();
    for (int i = e0 + threadIdx.x; i < e1; i += BLOCK) {
        uint e = csrE[i];                       // L2-hot re-read
        int pos = atomicAdd(&cur[dl8[i]], 1);
        csr4[pos] = e;
    }
}

// ---- layer 1: agg(u_x)*di @ W1 + b1, relu, @W2, *di -> u2 fp16 ----
__global__ void layer1_pass(const float* __restrict__ u_x, const int* __restrict__ rowptr,
                            const uint* __restrict__ csr4, const float* __restrict__ dinv,
                            const float* __restrict__ W1, const float* __restrict__ b1,
                            const float* __restrict__ W2, __half* __restrict__ t_next, int nN) {
    __shared__ float W1s[4 * 32];
    __shared__ float W2s[32 * 32];
    __shared__ float b1s[32];
    __shared__ float hS[BLOCK / 64][32];
    if (threadIdx.x < 128) W1s[threadIdx.x] = W1[threadIdx.x];
    for (int i = threadIdx.x; i < 32 * 32; i += BLOCK) W2s[i] = W2[i];
    if (threadIdx.x < 32) b1s[threadIdx.x] = b1[threadIdx.x];
    __syncthreads();

    int wv = threadIdx.x >> 6, lane = threadIdx.x & 63;
    int n = blockIdx.x * (BLOCK / 64) + wv;
    if (n >= nN) return;

    int el = lane >> 2, comp = lane & 3;        // 16 edge slots x 4 components
    float di = dinv[n];
    int s0 = rowptr[n], s1 = rowptr[n + 1];
    float acc = (el == 0) ? u_x[(size_t)n * 4 + comp] : 0.0f;   // self: u_x[n]
    int j = s0;
    for (; j + 32 <= s1; j += 32) {
        uint ea = csr4[j + el], eb = csr4[j + 16 + el];
        acc = fmaf((float)(ea & 32767u) * WINV, u_x[(size_t)(ea >> 15) * 4 + comp], acc);
        acc = fmaf((float)(eb & 32767u) * WINV, u_x[(size_t)(eb >> 15) * 4 + comp], acc);
    }
    for (; j + 16 <= s1; j += 16) {
        uint e = csr4[j + el];
        acc = fmaf((float)(e & 32767u) * WINV, u_x[(size_t)(e >> 15) * 4 + comp], acc);
    }
    if (j + el < s1) {
        uint e = csr4[j + el];
        acc = fmaf((float)(e & 32767u) * WINV, u_x[(size_t)(e >> 15) * 4 + comp], acc);
    }
#pragma unroll
    for (int off = 4; off < 64; off <<= 1) acc += __shfl_xor(acc, off);
    float a0 = di * __shfl(acc, 0), a1 = di * __shfl(acc, 1);
    float a2c = di * __shfl(acc, 2), a3 = di * __shfl(acc, 3);

    int f = lane & 31, e2 = lane >> 5;
    float h = b1s[f];
    h = fmaf(a0, W1s[0 * 32 + f], h);
    h = fmaf(a1, W1s[1 * 32 + f], h);
    h = fmaf(a2c, W1s[2 * 32 + f], h);
    h = fmaf(a3, W1s[3 * 32 + f], h);
    h = fmaxf(h, 0.0f);
    if (lane < 32) hS[wv][f] = h;               // wave-private; DS ops in-order
    float o = 0.0f;
#pragma unroll
    for (int k = 0; k < 16; ++k) {
        int kk = e2 * 16 + k;
        o = fmaf(hS[wv][kk], W2s[kk * 32 + f], o);
    }
    o += __shfl_xor(o, 32);
    if (lane < 32) t_next[(size_t)n * 32 + f] = __float2half(di * o);   // u-table
}

// ---- fused layer pass over fp16 u-table: h = di*(Σ w·u[src] + u[n]) + b ----
template <bool LAST>
__global__ void layer_pass(const __half* __restrict__ t, const int* __restrict__ rowptr,
                           const uint* __restrict__ csr4, const float* __restrict__ dinv,
                           const float* __restrict__ b, const float* __restrict__ W,
                           __half* __restrict__ t_next, __half* __restrict__ stage, int nN) {
    __shared__ float Ws[32 * 32];
    __shared__ float hS[BLOCK / 64][32];
    if (!LAST) {
        for (int i = threadIdx.x; i < 32 * 32; i += BLOCK) Ws[i] = W[i];
        __syncthreads();
    }
    int wv = threadIdx.x >> 6, lane = threadIdx.x & 63;
    int e2 = lane >> 5, f = lane & 31;
    int n = blockIdx.x * (BLOCK / 64) + wv;
    if (n >= nN) return;

    float di = dinv[n];
    int s0 = rowptr[n], s1 = rowptr[n + 1];
    float acc = (e2 == 0) ? __half2float(t[(size_t)n * 32 + f]) : 0.0f;   // self: u[n]

    int j4 = s0;
    for (; j4 + 16 <= s1; j4 += 16) {           // 16 edges in flight per wave
        uint p[8]; float v[8];
#pragma unroll
        for (int u = 0; u < 8; ++u) p[u] = csr4[j4 + 2 * u + e2];
#pragma unroll
        for (int u = 0; u < 8; ++u) v[u] = __half2float(t[(size_t)(p[u] >> 15) * 32 + f]);
#pragma unroll
        for (int u = 0; u < 8; ++u) acc = fmaf((float)(p[u] & 32767u) * WINV, v[u], acc);
    }
    for (; j4 + 4 <= s1; j4 += 4) {
        uint p[2]; float v[2];
#pragma unroll
        for (int u = 0; u < 2; ++u) p[u] = csr4[j4 + 2 * u + e2];
#pragma unroll
        for (int u = 0; u < 2; ++u) v[u] = __half2float(t[(size_t)(p[u] >> 15) * 32 + f]);
#pragma unroll
        for (int u = 0; u < 2; ++u) acc = fmaf((float)(p[u] & 32767u) * WINV, v[u], acc);
    }
    for (int j = j4 + e2; j < s1; j += 2) {
        uint p = csr4[j];
        acc = fmaf((float)(p & 32767u) * WINV, __half2float(t[(size_t)(p >> 15) * 32 + f]), acc);
    }

    acc += __shfl_xor(acc, 32);
    float h = di * acc + b[f];

    if (LAST) {
        if (lane < 32) stage[(size_t)n * 32 + f] = __float2half(h);
    } else {
        h = fmaxf(h, 0.0f);
        if (lane < 32) hS[wv][f] = h;
        float o = 0.0f;
#pragma unroll
        for (int k = 0; k < 16; ++k) {
            int kk = e2 * 16 + k;
            o = fmaf(hS[wv][kk], Ws[kk * 32 + f], o);
        }
        o += __shfl_xor(o, 32);
        if (lane < 32) t_next[(size_t)n * 32 + f] = __float2half(di * o);   // u-table
    }
}

// ---- pooling: LDS-privatized windows (batch sorted), fp16 input ----
__global__ void pool_kernel(const __half* __restrict__ stage, const int* __restrict__ batch,
                            float* __restrict__ sums, float* __restrict__ cnt, int nN) {
    __shared__ float accS[PB][32];
    __shared__ float cntS[PB];
    __shared__ int g0s;
    int n0 = blockIdx.x * PB;
    for (int i = threadIdx.x; i < PB * 32; i += BLOCK) ((float*)accS)[i] = 0.0f;
    for (int i = threadIdx.x; i < PB; i += BLOCK) cntS[i] = 0.0f;
    if (threadIdx.x == 0) g0s = batch[n0];
    __syncthreads();
    int g0 = g0s;
    int f = threadIdx.x & 31, sub = threadIdx.x >> 5;
    for (int k = 0; k < PB / 8; ++k) {
        int n = n0 + sub + k * 8;
        if (n < nN) {
            int g = batch[n];
            int off = g - g0;
            float v = __half2float(stage[(size_t)n * 32 + f]);
            if (off < PB) {
                atomicAdd(&accS[off][f], v);
                if (f == 0) atomicAdd(&cntS[off], 1.0f);
            } else {
                atomicAdd(&sums[(size_t)g * 32 + f], v);
                if (f == 0) atomicAdd(&cnt[g], 1.0f);
            }
        }
    }
    __syncthreads();
    int nLast = min(n0 + PB, nN) - 1;
    int range = min(batch[nLast] - g0, PB - 1);
    for (int s = sub; s <= range; s += 8) {
        atomicAdd(&sums[(size_t)(g0 + s) * 32 + f], accS[s][f]);
        if (f == 0) atomicAdd(&cnt[g0 + s], cntS[s]);
    }
}

// ---- classifier ----
__global__ void final_kernel(const float* __restrict__ sums, const float* __restrict__ cnt,
                             const float* __restrict__ lin_w, const float* __restrict__ lin_b,
                             float* __restrict__ out, int G) {
    int g = blockIdx.x * blockDim.x + threadIdx.x;
    if (g >= G) return;
    float c = fmaxf(cnt[g], 1.0f);
    float inv = 1.0f / c;
    float l0 = lin_b[0], l1 = lin_b[1], l2 = lin_b[2];
#pragma unroll
    for (int f = 0; f < 32; ++f) {
        float m = sums[g * 32 + f] * inv;
        l0 = fmaf(m, lin_w[f * 3 + 0], l0);
        l1 = fmaf(m, lin_w[f * 3 + 1], l1);
        l2 = fmaf(m, lin_w[f * 3 + 2], l2);
    }
    float mx = fmaxf(l0, fmaxf(l1, l2));
    float e0 = expf(l0 - mx), e1 = expf(l1 - mx), e2 = expf(l2 - mx);
    float s = 1.0f / (e0 + e1 + e2);
    out[g * 3 + 0] = e0 * s;
    out[g * 3 + 1] = e1 * s;
    out[g * 3 + 2] = e2 * s;
}

// ---------------- launch ----------------

extern "C" void kernel_launch(void* const* d_in, const int* in_sizes, int n_in,
                              void* d_out, int out_size, void* d_ws, size_t ws_size,
                              hipStream_t stream) {
    const float* x     = (const float*)d_in[0];
    const int*   ei    = (const int*)d_in[1];
    const float* ew    = (const float*)d_in[2];
    const int*   batch = (const int*)d_in[3];
    const float* W1    = (const float*)d_in[4];
    const float* b1    = (const float*)d_in[5];
    const float* W2    = (const float*)d_in[6];
    const float* b2    = (const float*)d_in[7];
    const float* W3    = (const float*)d_in[8];
    const float* b3    = (const float*)d_in[9];
    const float* lin_w = (const float*)d_in[10];
    const float* lin_b = (const float*)d_in[11];
    float* out = (float*)d_out;

    const int nN = in_sizes[0] / 4;       // 100000
    const int nE = in_sizes[2];           // 2500000
    const int G  = out_size / 3;          // 1000
    const int* row = ei;
    const int* col = ei + nE;

    const int NBUK = (nN + BN - 1) / BN;          // 782
    const int C    = (nE + CHUNK - 1) / CHUNK;    // 306

    // workspace layout
    char* wsb = (char*)d_ws;
    uint*   csrE   = (uint*)wsb;                                 // [nE]    10 MB
    uint*   csr4   = csrE + nE;                                  // [nE]    10 MB
    float*  u_x    = (float*)(csr4 + nE);                        // [nN*4]  1.6 MB
    __half* t_a    = (__half*)(u_x + (size_t)nN * 4);            // [nN*32] 6.4 MB
    __half* t_b    = t_a + (size_t)nN * 32;                      // [nN*32] 6.4 MB
    __half* stage  = t_b + (size_t)nN * 32;                      // [nN*32] 6.4 MB
    unsigned char* dl8 = (unsigned char*)(stage + (size_t)nN * 32); // [nE] 2.5 MB
    int*    cntmat = (int*)(dl8 + nE);                           // [C*NBUK] ~1 MB
    int*    tot    = cntmat + (size_t)C * NBUK;                  // [NBUK]
    int*    bb     = tot + NBUK;                                 // [NBUK+1]
    float*  dinv   = (float*)(bb + NBUK + 1);                    // [nN]
    int*    rowptr = (int*)(dinv + nN);                          // [nN+1]
    float*  sums   = (float*)(rowptr + nN + 1);                  // [G*32]
    float*  cnt    = sums + (size_t)G * 32;                      // [G]

    const int gW = (nN + (BLOCK / 64) - 1) / (BLOCK / 64);       // one wave per node

    // ---- build ----
    init_kernel<<<(G * 32 + BLOCK - 1) / BLOCK, BLOCK, 0, stream>>>(sums, cnt, rowptr, G, nN, nE);
    p1_kernel<<<C, BLOCK, 0, stream>>>(col, cntmat, nE, NBUK);
    p2a_kernel<<<(NBUK + 3) / 4, BLOCK, 0, stream>>>(cntmat, tot, C, NBUK);
    p2b_kernel<<<1, 1024, 0, stream>>>(tot, bb, NBUK, nE);
    p3_kernel<<<(C + 1) / 2, BLOCK, 0, stream>>>(row, col, ew, cntmat, bb, csrE, dl8, nE, NBUK);
    p4_kernel<<<NBUK, BLOCK, 0, stream>>>(csrE, dl8, bb, x, u_x, dinv, rowptr, csr4, nN);

    // ---- layers ----
    layer1_pass<<<gW, BLOCK, 0, stream>>>(u_x, rowptr, csr4, dinv, W1, b1, W2, t_b, nN);
    layer_pass<false><<<gW, BLOCK, 0, stream>>>(t_b, rowptr, csr4, dinv, b2, W3, t_a, nullptr, nN);
    layer_pass<true><<<gW, BLOCK, 0, stream>>>(t_a, rowptr, csr4, dinv, b3, nullptr, nullptr, stage, nN);

    // ---- pooling + classifier ----
    pool_kernel<<<(nN + PB - 1) / PB, BLOCK, 0, stream>>>(stage, batch, sums, cnt, nN);
    final_kernel<<<(G + BLOCK - 1) / BLOCK, BLOCK, 0, stream>>>(sums, cnt, lin_w, lin_b, out, G);
}

// Round 11
// 352.023 us; speedup vs baseline: 1.0964x; 1.0718x over previous
//
#include <hip/hip_runtime.h>
#include <hip/hip_fp16.h>

typedef unsigned long long ull;
typedef unsigned int uint;

#define BLOCK 256
#define CHUNK 4096    // edges per p1/p3 chunk
#define BN 128        // nodes per destination bucket
#define PB 128        // nodes per pooling block
#define WINV (1.0f / 32768.0f)

// ---- init: zero sums/cnt, set rowptr tail ----
__global__ void init_kernel(float* __restrict__ sums, float* __restrict__ cnt,
                            int* __restrict__ rowptr, int G, int nN, int nE) {
    int i = blockIdx.x * BLOCK + threadIdx.x;
    if (i < G * 32) sums[i] = 0.f;
    if (i < G) cnt[i] = 0.f;
    if (i == 0) rowptr[nN] = nE;
}

// ---- p1: per-chunk bucket histogram (LDS atomics only) ----
__global__ void p1_kernel(const int* __restrict__ col, int* __restrict__ cntmat,
                          int nE, int NBUK) {
    __shared__ int hist[1024];
    for (int i = threadIdx.x; i < NBUK; i += BLOCK) hist[i] = 0;
    __syncthreads();
    int base = blockIdx.x * CHUNK;
    int end = min(base + CHUNK, nE);
    for (int e = base + threadIdx.x; e < end; e += BLOCK)
        atomicAdd(&hist[col[e] >> 7], 1);
    __syncthreads();
    for (int i = threadIdx.x; i < NBUK; i += BLOCK)
        cntmat[(size_t)blockIdx.x * NBUK + i] = hist[i];
}

// ---- p2a: per-bucket scan over chunks, one wave per bucket ----
__global__ void p2a_kernel(int* __restrict__ cntmat, int* __restrict__ tot, int C, int NBUK) {
    int wv = threadIdx.x >> 6, lane = threadIdx.x & 63;
    int b = blockIdx.x * 4 + wv;
    if (b >= NBUK) return;
    int running = 0;
    for (int seg = 0; seg < C; seg += 64) {
        int c = seg + lane;
        int v = (c < C) ? cntmat[(size_t)c * NBUK + b] : 0;
        int s = v;
#pragma unroll
        for (int off = 1; off < 64; off <<= 1) {
            int u = __shfl_up(s, off);
            if (lane >= off) s += u;
        }
        if (c < C) cntmat[(size_t)c * NBUK + b] = running + (s - v);
        running += __shfl(s, 63);
    }
    if (lane == 0) tot[b] = running;
}

// ---- p2b: exclusive scan of totals -> base[] ----
__global__ void p2b_kernel(const int* __restrict__ tot, int* __restrict__ bb, int NBUK, int total) {
    __shared__ int s[1024];
    int t = threadIdx.x;
    int v = (t < NBUK) ? tot[t] : 0;
    s[t] = v;
    __syncthreads();
    for (int off = 1; off < 1024; off <<= 1) {
        int u = (t >= off) ? s[t - off] : 0;
        __syncthreads();
        s[t] += u;
        __syncthreads();
    }
    if (t < NBUK) bb[t] = s[t] - v;
    if (t == 0) bb[NBUK] = total;
}

// ---- p3: scatter edges into bucket-sorted order, quantizing w at the source ----
// ent = [dl:7]<<32 | [src:17]<<15 | wq:15  (low 32 bits == final csr4 word)
__global__ void p3_kernel(const int* __restrict__ row, const int* __restrict__ col,
                          const float* __restrict__ w, const int* __restrict__ cntmat,
                          const int* __restrict__ bb, ull* __restrict__ sorted,
                          int nE, int NBUK) {
    __shared__ int cur[1024];
    for (int i = threadIdx.x; i < NBUK; i += BLOCK)
        cur[i] = cntmat[(size_t)blockIdx.x * NBUK + i] + bb[i];
    __syncthreads();
    int base = blockIdx.x * CHUNK;
    int end = min(base + CHUNK, nE);
    for (int e = base + threadIdx.x; e < end; e += BLOCK) {
        int c = col[e], r = row[e];
        float ww = w[e];
        int b = c >> 7;
        int wq = min((int)(ww * 32768.0f + 0.5f), 32767);
        int pos = atomicAdd(&cur[b], 1);
        sorted[pos] = ((ull)(uint)(c & 127) << 32) | ((ull)(uint)r << 15) | (ull)(uint)wq;
    }
}

// ---- p4: degree(from wq)+dinv+rowptr (1 packed LDS atomic/edge), then final
//      per-node csr4 (bucket-local permutation), plus u_x epilogue ----
__global__ void p4_kernel(const ull* __restrict__ sorted, const int* __restrict__ bb,
                          const float* __restrict__ x, float* __restrict__ u_x,
                          float* __restrict__ dinv, int* __restrict__ rowptr,
                          uint* __restrict__ csr4, int nN) {
    __shared__ uint pk[BN];        // cnt<<24 | sum(wq)  (sum < 2^24 for deg<512)
    __shared__ int scanS[BN];
    __shared__ int cur[BN];
    if (threadIdx.x < BN) pk[threadIdx.x] = 0u;
    __syncthreads();
    int b = blockIdx.x;
    int e0 = bb[b], e1 = bb[b + 1];
    for (int i = e0 + threadIdx.x; i < e1; i += BLOCK) {
        ull ent = sorted[i];
        atomicAdd(&pk[(int)(ent >> 32) & 127], (1u << 24) | ((uint)ent & 32767u));
    }
    __syncthreads();
    int cnt = 0;
    if (threadIdx.x < BN) { cnt = (int)(pk[threadIdx.x] >> 24); scanS[threadIdx.x] = cnt; }
    __syncthreads();
    for (int off = 1; off < BN; off <<= 1) {
        int u = 0;
        if (threadIdx.x < BN && threadIdx.x >= off) u = scanS[threadIdx.x - off];
        __syncthreads();
        if (threadIdx.x < BN) scanS[threadIdx.x] += u;
        __syncthreads();
    }
    if (threadIdx.x < BN) {
        int n = b * BN + threadIdx.x;
        if (n < nN) {
            float di = rsqrtf(1.0f + (float)(pk[threadIdx.x] & 0xFFFFFFu) * WINV);
            dinv[n] = di;
            int rp = e0 + scanS[threadIdx.x] - cnt;
            rowptr[n] = rp;
            cur[threadIdx.x] = rp;
            float4 xv = ((const float4*)x)[n];
            ((float4*)u_x)[n] = make_float4(xv.x * di, xv.y * di, xv.z * di, xv.w * di);
        }
    }
    __syncthreads();
    for (int i = e0 + threadIdx.x; i < e1; i += BLOCK) {
        ull ent = sorted[i];                    // L2-hot re-read
        int pos = atomicAdd(&cur[(int)(ent >> 32) & 127], 1);
        csr4[pos] = (uint)ent;                  // src<<15 | wq
    }
}

// ---- layer 1: agg(u_x)*di @ W1 + b1, relu, @W2, *di -> u2 fp16 ----
__global__ void layer1_pass(const float* __restrict__ u_x, const int* __restrict__ rowptr,
                            const uint* __restrict__ csr4, const float* __restrict__ dinv,
                            const float* __restrict__ W1, const float* __restrict__ b1,
                            const float* __restrict__ W2, __half* __restrict__ t_next, int nN) {
    __shared__ float W1s[4 * 32];
    __shared__ float W2s[32 * 32];
    __shared__ float b1s[32];
    __shared__ float hS[BLOCK / 64][32];
    if (threadIdx.x < 128) W1s[threadIdx.x] = W1[threadIdx.x];
    for (int i = threadIdx.x; i < 32 * 32; i += BLOCK) W2s[i] = W2[i];
    if (threadIdx.x < 32) b1s[threadIdx.x] = b1[threadIdx.x];
    __syncthreads();

    int wv = threadIdx.x >> 6, lane = threadIdx.x & 63;
    int n = blockIdx.x * (BLOCK / 64) + wv;
    if (n >= nN) return;

    int el = lane >> 2, comp = lane & 3;        // 16 edge slots x 4 components
    float di = dinv[n];
    int s0 = rowptr[n], s1 = rowptr[n + 1];
    float acc = (el == 0) ? u_x[(size_t)n * 4 + comp] : 0.0f;   // self: u_x[n]
    int j = s0;
    for (; j + 32 <= s1; j += 32) {
        uint ea = csr4[j + el], eb = csr4[j + 16 + el];
        acc = fmaf((float)(ea & 32767u) * WINV, u_x[(size_t)(ea >> 15) * 4 + comp], acc);
        acc = fmaf((float)(eb & 32767u) * WINV, u_x[(size_t)(eb >> 15) * 4 + comp], acc);
    }
    for (; j + 16 <= s1; j += 16) {
        uint e = csr4[j + el];
        acc = fmaf((float)(e & 32767u) * WINV, u_x[(size_t)(e >> 15) * 4 + comp], acc);
    }
    if (j + el < s1) {
        uint e = csr4[j + el];
        acc = fmaf((float)(e & 32767u) * WINV, u_x[(size_t)(e >> 15) * 4 + comp], acc);
    }
#pragma unroll
    for (int off = 4; off < 64; off <<= 1) acc += __shfl_xor(acc, off);
    float a0 = di * __shfl(acc, 0), a1 = di * __shfl(acc, 1);
    float a2c = di * __shfl(acc, 2), a3 = di * __shfl(acc, 3);

    int f = lane & 31, e2 = lane >> 5;
    float h = b1s[f];
    h = fmaf(a0, W1s[0 * 32 + f], h);
    h = fmaf(a1, W1s[1 * 32 + f], h);
    h = fmaf(a2c, W1s[2 * 32 + f], h);
    h = fmaf(a3, W1s[3 * 32 + f], h);
    h = fmaxf(h, 0.0f);
    if (lane < 32) hS[wv][f] = h;               // wave-private; DS ops in-order
    float o = 0.0f;
#pragma unroll
    for (int k = 0; k < 16; ++k) {
        int kk = e2 * 16 + k;
        o = fmaf(hS[wv][kk], W2s[kk * 32 + f], o);
    }
    o += __shfl_xor(o, 32);
    if (lane < 32) t_next[(size_t)n * 32 + f] = __float2half(di * o);   // u-table
}

// ---- fused layer pass over fp16 u-table: h = di*(Σ w·u[src] + u[n]) + b ----
template <bool LAST>
__global__ void layer_pass(const __half* __restrict__ t, const int* __restrict__ rowptr,
                           const uint* __restrict__ csr4, const float* __restrict__ dinv,
                           const float* __restrict__ b, const float* __restrict__ W,
                           __half* __restrict__ t_next, __half* __restrict__ stage, int nN) {
    __shared__ float Ws[32 * 32];
    __shared__ float hS[BLOCK / 64][32];
    if (!LAST) {
        for (int i = threadIdx.x; i < 32 * 32; i += BLOCK) Ws[i] = W[i];
        __syncthreads();
    }
    int wv = threadIdx.x >> 6, lane = threadIdx.x & 63;
    int e2 = lane >> 5, f = lane & 31;
    int n = blockIdx.x * (BLOCK / 64) + wv;
    if (n >= nN) return;

    float di = dinv[n];
    int s0 = rowptr[n], s1 = rowptr[n + 1];
    float acc = (e2 == 0) ? __half2float(t[(size_t)n * 32 + f]) : 0.0f;   // self: u[n]

    int j4 = s0;
    for (; j4 + 16 <= s1; j4 += 16) {           // 16 edges in flight per wave
        uint p[8]; float v[8];
#pragma unroll
        for (int u = 0; u < 8; ++u) p[u] = csr4[j4 + 2 * u + e2];
#pragma unroll
        for (int u = 0; u < 8; ++u) v[u] = __half2float(t[(size_t)(p[u] >> 15) * 32 + f]);
#pragma unroll
        for (int u = 0; u < 8; ++u) acc = fmaf((float)(p[u] & 32767u) * WINV, v[u], acc);
    }
    for (; j4 + 4 <= s1; j4 += 4) {
        uint p[2]; float v[2];
#pragma unroll
        for (int u = 0; u < 2; ++u) p[u] = csr4[j4 + 2 * u + e2];
#pragma unroll
        for (int u = 0; u < 2; ++u) v[u] = __half2float(t[(size_t)(p[u] >> 15) * 32 + f]);
#pragma unroll
        for (int u = 0; u < 2; ++u) acc = fmaf((float)(p[u] & 32767u) * WINV, v[u], acc);
    }
    for (int j = j4 + e2; j < s1; j += 2) {
        uint p = csr4[j];
        acc = fmaf((float)(p & 32767u) * WINV, __half2float(t[(size_t)(p >> 15) * 32 + f]), acc);
    }

    acc += __shfl_xor(acc, 32);
    float h = di * acc + b[f];

    if (LAST) {
        if (lane < 32) stage[(size_t)n * 32 + f] = __float2half(h);
    } else {
        h = fmaxf(h, 0.0f);
        if (lane < 32) hS[wv][f] = h;
        float o = 0.0f;
#pragma unroll
        for (int k = 0; k < 16; ++k) {
            int kk = e2 * 16 + k;
            o = fmaf(hS[wv][kk], Ws[kk * 32 + f], o);
        }
        o += __shfl_xor(o, 32);
        if (lane < 32) t_next[(size_t)n * 32 + f] = __float2half(di * o);   // u-table
    }
}

// ---- pooling: LDS-privatized windows (batch sorted), fp16 input ----
__global__ void pool_kernel(const __half* __restrict__ stage, const int* __restrict__ batch,
                            float* __restrict__ sums, float* __restrict__ cnt, int nN) {
    __shared__ float accS[PB][32];
    __shared__ float cntS[PB];
    __shared__ int g0s;
    int n0 = blockIdx.x * PB;
    for (int i = threadIdx.x; i < PB * 32; i += BLOCK) ((float*)accS)[i] = 0.0f;
    for (int i = threadIdx.x; i < PB; i += BLOCK) cntS[i] = 0.0f;
    if (threadIdx.x == 0) g0s = batch[n0];
    __syncthreads();
    int g0 = g0s;
    int f = threadIdx.x & 31, sub = threadIdx.x >> 5;
    for (int k = 0; k < PB / 8; ++k) {
        int n = n0 + sub + k * 8;
        if (n < nN) {
            int g = batch[n];
            int off = g - g0;
            float v = __half2float(stage[(size_t)n * 32 + f]);
            if (off < PB) {
                atomicAdd(&accS[off][f], v);
                if (f == 0) atomicAdd(&cntS[off], 1.0f);
            } else {
                atomicAdd(&sums[(size_t)g * 32 + f], v);
                if (f == 0) atomicAdd(&cnt[g], 1.0f);
            }
        }
    }
    __syncthreads();
    int nLast = min(n0 + PB, nN) - 1;
    int range = min(batch[nLast] - g0, PB - 1);
    for (int s = sub; s <= range; s += 8) {
        atomicAdd(&sums[(size_t)(g0 + s) * 32 + f], accS[s][f]);
        if (f == 0) atomicAdd(&cnt[g0 + s], cntS[s]);
    }
}

// ---- classifier ----
__global__ void final_kernel(const float* __restrict__ sums, const float* __restrict__ cnt,
                             const float* __restrict__ lin_w, const float* __restrict__ lin_b,
                             float* __restrict__ out, int G) {
    int g = blockIdx.x * blockDim.x + threadIdx.x;
    if (g >= G) return;
    float c = fmaxf(cnt[g], 1.0f);
    float inv = 1.0f / c;
    float l0 = lin_b[0], l1 = lin_b[1], l2 = lin_b[2];
#pragma unroll
    for (int f = 0; f < 32; ++f) {
        float m = sums[g * 32 + f] * inv;
        l0 = fmaf(m, lin_w[f * 3 + 0], l0);
        l1 = fmaf(m, lin_w[f * 3 + 1], l1);
        l2 = fmaf(m, lin_w[f * 3 + 2], l2);
    }
    float mx = fmaxf(l0, fmaxf(l1, l2));
    float e0 = expf(l0 - mx), e1 = expf(l1 - mx), e2 = expf(l2 - mx);
    float s = 1.0f / (e0 + e1 + e2);
    out[g * 3 + 0] = e0 * s;
    out[g * 3 + 1] = e1 * s;
    out[g * 3 + 2] = e2 * s;
}

// ---------------- launch ----------------

extern "C" void kernel_launch(void* const* d_in, const int* in_sizes, int n_in,
                              void* d_out, int out_size, void* d_ws, size_t ws_size,
                              hipStream_t stream) {
    const float* x     = (const float*)d_in[0];
    const int*   ei    = (const int*)d_in[1];
    const float* ew    = (const float*)d_in[2];
    const int*   batch = (const int*)d_in[3];
    const float* W1    = (const float*)d_in[4];
    const float* b1    = (const float*)d_in[5];
    const float* W2    = (const float*)d_in[6];
    const float* b2    = (const float*)d_in[7];
    const float* W3    = (const float*)d_in[8];
    const float* b3    = (const float*)d_in[9];
    const float* lin_w = (const float*)d_in[10];
    const float* lin_b = (const float*)d_in[11];
    float* out = (float*)d_out;

    const int nN = in_sizes[0] / 4;       // 100000
    const int nE = in_sizes[2];           // 2500000
    const int G  = out_size / 3;          // 1000
    const int* row = ei;
    const int* col = ei + nE;

    const int NBUK = (nN + BN - 1) / BN;          // 782
    const int C    = (nE + CHUNK - 1) / CHUNK;    // 611

    // workspace layout
    char* wsb = (char*)d_ws;
    ull*    sorted = (ull*)wsb;                                  // [nE]    20 MB
    uint*   csr4   = (uint*)(sorted + nE);                       // [nE]    10 MB
    float*  u_x    = (float*)(csr4 + nE);                        // [nN*4]  1.6 MB
    __half* t_a    = (__half*)(u_x + (size_t)nN * 4);            // [nN*32] 6.4 MB
    __half* t_b    = t_a + (size_t)nN * 32;                      // [nN*32] 6.4 MB
    __half* stage  = t_b + (size_t)nN * 32;                      // [nN*32] 6.4 MB
    int*    cntmat = (int*)(stage + (size_t)nN * 32);            // [C*NBUK] ~1.9 MB
    int*    tot    = cntmat + (size_t)C * NBUK;                  // [NBUK]
    int*    bb     = tot + NBUK;                                 // [NBUK+1]
    float*  dinv   = (float*)(bb + NBUK + 1);                    // [nN]
    int*    rowptr = (int*)(dinv + nN);                          // [nN+1]
    float*  sums   = (float*)(rowptr + nN + 1);                  // [G*32]
    float*  cnt    = sums + (size_t)G * 32;                      // [G]

    const int gW = (nN + (BLOCK / 64) - 1) / (BLOCK / 64);       // one wave per node

    // ---- build ----
    init_kernel<<<(G * 32 + BLOCK - 1) / BLOCK, BLOCK, 0, stream>>>(sums, cnt, rowptr, G, nN, nE);
    p1_kernel<<<C, BLOCK, 0, stream>>>(col, cntmat, nE, NBUK);
    p2a_kernel<<<(NBUK + 3) / 4, BLOCK, 0, stream>>>(cntmat, tot, C, NBUK);
    p2b_kernel<<<1, 1024, 0, stream>>>(tot, bb, NBUK, nE);
    p3_kernel<<<C, BLOCK, 0, stream>>>(row, col, ew, cntmat, bb, sorted, nE, NBUK);
    p4_kernel<<<NBUK, BLOCK, 0, stream>>>(sorted, bb, x, u_x, dinv, rowptr, csr4, nN);

    // ---- layers ----
    layer1_pass<<<gW, BLOCK, 0, stream>>>(u_x, rowptr, csr4, dinv, W1, b1, W2, t_b, nN);
    layer_pass<false><<<gW, BLOCK, 0, stream>>>(t_b, rowptr, csr4, dinv, b2, W3, t_a, nullptr, nN);
    layer_pass<true><<<gW, BLOCK, 0, stream>>>(t_a, rowptr, csr4, dinv, b3, nullptr, nullptr, stage, nN);

    // ---- pooling + classifier ----
    pool_kernel<<<(nN + PB - 1) / PB, BLOCK, 0, stream>>>(stage, batch, sums, cnt, nN);
    final_kernel<<<(G + BLOCK - 1) / BLOCK, BLOCK, 0, stream>>>(sums, cnt, lin_w, lin_b, out, G);
}